// Round 3
// baseline (337.902 us; speedup 1.0000x reference)
//
#include <hip/hip_runtime.h>
#include <math.h>

#define NUM_KV_HEADS 8
#define HEAD_DIM 128
#define HD (NUM_KV_HEADS * HEAD_DIM)
#define BLOCK_SZ 16
#define MODEL_CTX 4096
#define CHUNK 128            // tokens per split-K chunk
#define BLKS_PER_CHUNK (CHUNK / BLOCK_SZ)   // 8

// Kernel 0: rope cos/sin table. tab[t][f] = {cos(t*invf_f), sin(t*invf_f)},
// f in [0,64). Layout float2 -> float4 at (t*128 + 4*sl) gives
// {cos(f0),sin(f0),cos(f1),sin(f1)} for f0=2sl, f1=2sl+1.
__global__ void rope_table(float* __restrict__ tab, int ntab) {
    const int idx = blockIdx.x * 256 + threadIdx.x;   // t*64 + f
    if (idx >= ntab * 64) return;
    const int t = idx >> 6;
    const int f = idx & 63;
    const float inv = expf(-9.210340371976184f * (float)f * (1.0f / 64.0f));
    float s, c;
    sincosf((float)t * inv, &s, &c);
    tab[2 * idx]     = c;
    tab[2 * idx + 1] = s;
}

// Kernel 1: per-(chunk, b*h) partial attention.
// Two strictly separated phases (K-scores, then V-accumulate) to keep the
// LLC streaming-friendly (K misses, V hits lines resident from previous
// iteration) -- this is what kept FETCH at ~135MB in the 105us version.
// 16-lane group owns one token at a time; lane m covers dims {4m..4m+3}
// and {64+4m..64+4m+3} via float4 loads. Scores live in registers between
// phases; softmax is OFFLINE (wave max known before PV) -- no rescale chain.
__global__ __launch_bounds__(256, 6)
void attn_partial(const float* __restrict__ q,
                  const float* __restrict__ knew,
                  const float* __restrict__ vnew,
                  const float* __restrict__ kcache,
                  const float* __restrict__ vcache,
                  const int* __restrict__ btab,
                  const int* __restrict__ seqlen_p,
                  const float* __restrict__ tab,
                  int nbps,
                  float* __restrict__ o_part,    // [B*H][n_chunks][128]
                  float* __restrict__ m_part,    // [B*H][n_chunks]
                  float* __restrict__ l_part,    // [B*H][n_chunks]
                  int n_chunks)
{
    const int chunk = blockIdx.x;
    const int bh    = blockIdx.y;
    const int b     = bh / NUM_KV_HEADS;
    const int h     = bh % NUM_KV_HEADS;
    const int tid   = threadIdx.x;
    const int lane  = tid & 63;
    const int wave  = tid >> 6;
    const int g     = lane >> 4;     // token group 0..3 within wave
    const int m16   = lane & 15;     // lane within group

    __shared__ __align__(16) float wo[4][HEAD_DIM];
    __shared__ float wm[4], wl[4];

    const int seq_len = *seqlen_p;
    const int rem = (seq_len - 1) & (BLOCK_SZ - 1);
    const int T   = (nbps - 1) * BLOCK_SZ + rem + 1;

    // ---- roped q fragment (pos MODEL_CTX-1) ----
    const float* qb = q + (size_t)b * HD + h * HEAD_DIM;
    const float4 q1  = *(const float4*)(qb + 4 * m16);
    const float4 q2  = *(const float4*)(qb + 64 + 4 * m16);
    const float4 tq1 = *(const float4*)(tab + (size_t)(MODEL_CTX - 1) * 128 + 8 * m16);
    const float4 tq2 = *(const float4*)(tab + (size_t)(MODEL_CTX - 1) * 128 + 8 * m16 + 4);
    float4 qr1, qr2;
    qr1.x = q1.x * tq1.x - q2.x * tq1.y;  qr2.x = q2.x * tq1.x + q1.x * tq1.y;
    qr1.y = q1.y * tq1.z - q2.y * tq1.w;  qr2.y = q2.y * tq1.z + q1.y * tq1.w;
    qr1.z = q1.z * tq2.x - q2.z * tq2.y;  qr2.z = q2.z * tq2.x + q1.z * tq2.y;
    qr1.w = q1.w * tq2.z - q2.w * tq2.w;  qr2.w = q2.w * tq2.z + q1.w * tq2.w;

    const int t0 = chunk * CHUNK;
    const size_t head_off = (size_t)h * HEAD_DIM;
    const float scale = 0.08838834764831845f;   // 1/sqrt(128)

    // wave covers 32 tokens = 2 cache blocks
    const int bti  = b * nbps + chunk * BLKS_PER_CHUNK;
    const int blk0 = btab[bti + wave * 2];
    const int blk1 = btab[bti + wave * 2 + 1];
    const float* kb0 = kcache + (size_t)blk0 * BLOCK_SZ * HD + head_off;
    const float* kb1 = kcache + (size_t)blk1 * BLOCK_SZ * HD + head_off;
    const float* vb0 = vcache + (size_t)blk0 * BLOCK_SZ * HD + head_off;
    const float* vb1 = vcache + (size_t)blk1 * BLOCK_SZ * HD + head_off;
    const float* knb = knew + (size_t)b * HD + head_off;
    const float* vnb = vnew + (size_t)b * HD + head_off;

    const int tw = t0 + wave * 32;   // wave's first token

    // ================= phase 1: K -> scores (registers) =================
    float s[8];
    #pragma unroll
    for (int jj = 0; jj < 4; jj++) {
        const int locA = 8 * jj + g;          // 0..31 within wave
        const int locB = locA + 4;
        const int tA = tw + locA;
        const int tB = tw + locB;
        const bool nlA = (tA >= T - 1);
        const bool nlB = (tB >= T - 1);
        const float* kpA = nlA ? knb : ((locA < 16 ? kb0 : kb1) + (size_t)(locA & 15) * HD);
        const float* kpB = nlB ? knb : ((locB < 16 ? kb0 : kb1) + (size_t)(locB & 15) * HD);
        const int ttA = nlA ? (MODEL_CTX - 1) : tA;
        const int ttB = nlB ? (MODEL_CTX - 1) : tB;

        // issue the pair's 8 loads up front
        const float4 kA1 = *(const float4*)(kpA + 4 * m16);
        const float4 kA2 = *(const float4*)(kpA + 64 + 4 * m16);
        const float4 kB1 = *(const float4*)(kpB + 4 * m16);
        const float4 kB2 = *(const float4*)(kpB + 64 + 4 * m16);
        const float4 cA1 = *(const float4*)(tab + (size_t)ttA * 128 + 8 * m16);
        const float4 cA2 = *(const float4*)(tab + (size_t)ttA * 128 + 8 * m16 + 4);
        const float4 cB1 = *(const float4*)(tab + (size_t)ttB * 128 + 8 * m16);
        const float4 cB2 = *(const float4*)(tab + (size_t)ttB * 128 + 8 * m16 + 4);

        float dA =
            (kA1.x * cA1.x - kA2.x * cA1.y) * qr1.x + (kA2.x * cA1.x + kA1.x * cA1.y) * qr2.x
          + (kA1.y * cA1.z - kA2.y * cA1.w) * qr1.y + (kA2.y * cA1.z + kA1.y * cA1.w) * qr2.y
          + (kA1.z * cA2.x - kA2.z * cA2.y) * qr1.z + (kA2.z * cA2.x + kA1.z * cA2.y) * qr2.z
          + (kA1.w * cA2.z - kA2.w * cA2.w) * qr1.w + (kA2.w * cA2.z + kA1.w * cA2.w) * qr2.w;
        float dB =
            (kB1.x * cB1.x - kB2.x * cB1.y) * qr1.x + (kB2.x * cB1.x + kB1.x * cB1.y) * qr2.x
          + (kB1.y * cB1.z - kB2.y * cB1.w) * qr1.y + (kB2.y * cB1.z + kB1.y * cB1.w) * qr2.y
          + (kB1.z * cB2.x - kB2.z * cB2.y) * qr1.z + (kB2.z * cB2.x + kB1.z * cB2.y) * qr2.z
          + (kB1.w * cB2.z - kB2.w * cB2.w) * qr1.w + (kB2.w * cB2.z + kB1.w * cB2.w) * qr2.w;

        #pragma unroll
        for (int off = 1; off < 16; off <<= 1) {
            dA += __shfl_xor(dA, off, 64);
            dB += __shfl_xor(dB, off, 64);
        }
        s[2 * jj]     = (tA < T) ? dA * scale : -INFINITY;
        s[2 * jj + 1] = (tB < T) ? dB * scale : -INFINITY;
    }

    // ---- wave max (offline softmax) ----
    float m = s[0];
    #pragma unroll
    for (int i = 1; i < 8; i++) m = fmaxf(m, s[i]);
    m = fmaxf(m, __shfl_xor(m, 16, 64));
    m = fmaxf(m, __shfl_xor(m, 32, 64));     // wave-wide max, all lanes

    float p[8];
    float l = 0.f;
    #pragma unroll
    for (int i = 0; i < 8; i++) { p[i] = __expf(s[i] - m); l += p[i]; }

    // strict block-level phase separation: no V load before all K loads done
    __syncthreads();

    // ================= phase 2: p * V =================
    float4 o1 = {0.f, 0.f, 0.f, 0.f};
    float4 o2 = {0.f, 0.f, 0.f, 0.f};
    #pragma unroll
    for (int jj = 0; jj < 4; jj++) {
        const int locA = 8 * jj + g;
        const int locB = locA + 4;
        const int tA = tw + locA;
        const int tB = tw + locB;
        const float* vpA = (tA >= T - 1) ? vnb : ((locA < 16 ? vb0 : vb1) + (size_t)(locA & 15) * HD);
        const float* vpB = (tB >= T - 1) ? vnb : ((locB < 16 ? vb0 : vb1) + (size_t)(locB & 15) * HD);

        const float4 vA1 = *(const float4*)(vpA + 4 * m16);
        const float4 vA2 = *(const float4*)(vpA + 64 + 4 * m16);
        const float4 vB1 = *(const float4*)(vpB + 4 * m16);
        const float4 vB2 = *(const float4*)(vpB + 64 + 4 * m16);

        const float pA = p[2 * jj];
        const float pB = p[2 * jj + 1];
        o1.x += pA * vA1.x + pB * vB1.x;
        o1.y += pA * vA1.y + pB * vB1.y;
        o1.z += pA * vA1.z + pB * vB1.z;
        o1.w += pA * vA1.w + pB * vB1.w;
        o2.x += pA * vA2.x + pB * vB2.x;
        o2.y += pA * vA2.y + pB * vB2.y;
        o2.z += pA * vA2.z + pB * vB2.z;
        o2.w += pA * vA2.w + pB * vB2.w;
    }

    // ---- combine the 4 groups within the wave (same m16 = same dims) ----
    float lw = l;
    #pragma unroll
    for (int off = 16; off < 64; off <<= 1) {
        lw   += __shfl_xor(lw, off, 64);
        o1.x += __shfl_xor(o1.x, off, 64);
        o1.y += __shfl_xor(o1.y, off, 64);
        o1.z += __shfl_xor(o1.z, off, 64);
        o1.w += __shfl_xor(o1.w, off, 64);
        o2.x += __shfl_xor(o2.x, off, 64);
        o2.y += __shfl_xor(o2.y, off, 64);
        o2.z += __shfl_xor(o2.z, off, 64);
        o2.w += __shfl_xor(o2.w, off, 64);
    }

    if (g == 0) {
        *(float4*)&wo[wave][4 * m16]      = o1;
        *(float4*)&wo[wave][64 + 4 * m16] = o2;
        if (m16 == 0) { wm[wave] = m; wl[wave] = lw; }
    }
    __syncthreads();

    // ---- cross-wave combine + store partials ----
    if (tid < HEAD_DIM) {
        const float m0 = wm[0], m1 = wm[1], m2 = wm[2], m3 = wm[3];
        const float M = fmaxf(fmaxf(m0, m1), fmaxf(m2, m3));
        const float w0 = __expf(m0 - M), w1 = __expf(m1 - M);
        const float w2 = __expf(m2 - M), w3 = __expf(m3 - M);
        const float num = w0 * wo[0][tid] + w1 * wo[1][tid]
                        + w2 * wo[2][tid] + w3 * wo[3][tid];
        o_part[((size_t)bh * n_chunks + chunk) * HEAD_DIM + tid] = num;
        if (tid == 0) {
            m_part[bh * n_chunks + chunk] = M;
            l_part[bh * n_chunks + chunk] = w0 * wl[0] + w1 * wl[1] + w2 * wl[2] + w3 * wl[3];
        }
    }
}

// Kernel 2: combine split-K partials.
__global__ void attn_combine(const float* __restrict__ o_part,
                             const float* __restrict__ m_part,
                             const float* __restrict__ l_part,
                             float* __restrict__ out,
                             int n_chunks)
{
    const int bh = blockIdx.x;
    const int d  = threadIdx.x;

    float M = -INFINITY;
    for (int c = 0; c < n_chunks; c++) M = fmaxf(M, m_part[bh * n_chunks + c]);
    float L = 0.f, num = 0.f;
    for (int c = 0; c < n_chunks; c++) {
        const float w = __expf(m_part[bh * n_chunks + c] - M);
        L   += l_part[bh * n_chunks + c] * w;
        num += w * o_part[((size_t)bh * n_chunks + c) * HEAD_DIM + d];
    }
    out[(size_t)bh * HEAD_DIM + d] = num / L;
}

extern "C" void kernel_launch(void* const* d_in, const int* in_sizes, int n_in,
                              void* d_out, int out_size, void* d_ws, size_t ws_size,
                              hipStream_t stream) {
    const float* q  = (const float*)d_in[0];
    const float* k  = (const float*)d_in[1];
    const float* v  = (const float*)d_in[2];
    const float* kc = (const float*)d_in[3];
    const float* vc = (const float*)d_in[4];
    const int* bt   = (const int*)d_in[5];
    const int* slp  = (const int*)d_in[7];

    const int B    = in_sizes[0] / HD;
    const int nbps = in_sizes[5] / B;                              // 256
    const int n_chunks = (nbps * BLOCK_SZ + CHUNK - 1) / CHUNK;    // 32
    const int BH = B * NUM_KV_HEADS;

    int ntab = nbps * BLOCK_SZ;
    if (ntab < MODEL_CTX) ntab = MODEL_CTX;

    float* tab    = (float*)d_ws;                                   // ntab*64*2 floats
    float* o_part = tab + (size_t)ntab * 128;
    float* m_part = o_part + (size_t)BH * n_chunks * HEAD_DIM;
    float* l_part = m_part + (size_t)BH * n_chunks;

    const int ttotal = ntab * 64;
    rope_table<<<(ttotal + 255) / 256, 256, 0, stream>>>(tab, ntab);

    dim3 g1(n_chunks, BH);
    attn_partial<<<g1, 256, 0, stream>>>(q, k, v, kc, vc, bt, slp, tab, nbps,
                                         o_part, m_part, l_part, n_chunks);
    attn_combine<<<dim3(BH), HEAD_DIM, 0, stream>>>(o_part, m_part, l_part,
                                                    (float*)d_out, n_chunks);
}

// Round 4
// 302.827 us; speedup vs baseline: 1.1158x; 1.1158x over previous
//
#include <hip/hip_runtime.h>
#include <math.h>

#define NUM_KV_HEADS 8
#define HEAD_DIM 128
#define HD (NUM_KV_HEADS * HEAD_DIM)
#define BLOCK_SZ 16
#define MODEL_CTX 4096
#define CHUNK 128            // tokens per split-K chunk
#define BLKS_PER_CHUNK (CHUNK / BLOCK_SZ)   // 8

// Kernel 0: rope cos/sin table. tab[t][f] = {cos(t*invf_f), sin(t*invf_f)},
// f in [0,64). Layout float2 -> float4 at (t*128 + 4*sl) gives
// {cos(f0),sin(f0),cos(f1),sin(f1)} for f0=2sl, f1=2sl+1.
__global__ void rope_table(float* __restrict__ tab, int ntab) {
    const int idx = blockIdx.x * 256 + threadIdx.x;   // t*64 + f
    if (idx >= ntab * 64) return;
    const int t = idx >> 6;
    const int f = idx & 63;
    const float inv = expf(-9.210340371976184f * (float)f * (1.0f / 64.0f));
    float s, c;
    sincosf((float)t * inv, &s, &c);
    tab[2 * idx]     = c;
    tab[2 * idx + 1] = s;
}

// Kernel 1: per-(chunk, b*h) partial attention.
// Structure identical to round 3; ONLY change is __launch_bounds__(256,4):
// the (256,6) 80-VGPR cap forced ~320B/thread of scratch spills, whose
// store+reload traffic was the 169MB WRITE_SIZE / +82MB FETCH_SIZE.
// 128-VGPR cap fits the ~80-reg peak working set -> no scratch.
__global__ __launch_bounds__(256, 4)
void attn_partial(const float* __restrict__ q,
                  const float* __restrict__ knew,
                  const float* __restrict__ vnew,
                  const float* __restrict__ kcache,
                  const float* __restrict__ vcache,
                  const int* __restrict__ btab,
                  const int* __restrict__ seqlen_p,
                  const float* __restrict__ tab,
                  int nbps,
                  float* __restrict__ o_part,    // [B*H][n_chunks][128]
                  float* __restrict__ m_part,    // [B*H][n_chunks]
                  float* __restrict__ l_part,    // [B*H][n_chunks]
                  int n_chunks)
{
    const int chunk = blockIdx.x;
    const int bh    = blockIdx.y;
    const int b     = bh / NUM_KV_HEADS;
    const int h     = bh % NUM_KV_HEADS;
    const int tid   = threadIdx.x;
    const int lane  = tid & 63;
    const int wave  = tid >> 6;
    const int g     = lane >> 4;     // token group 0..3 within wave
    const int m16   = lane & 15;     // lane within group

    __shared__ __align__(16) float wo[4][HEAD_DIM];
    __shared__ float wm[4], wl[4];

    const int seq_len = *seqlen_p;
    const int rem = (seq_len - 1) & (BLOCK_SZ - 1);
    const int T   = (nbps - 1) * BLOCK_SZ + rem + 1;

    // ---- roped q fragment (pos MODEL_CTX-1) ----
    const float* qb = q + (size_t)b * HD + h * HEAD_DIM;
    const float4 q1  = *(const float4*)(qb + 4 * m16);
    const float4 q2  = *(const float4*)(qb + 64 + 4 * m16);
    const float4 tq1 = *(const float4*)(tab + (size_t)(MODEL_CTX - 1) * 128 + 8 * m16);
    const float4 tq2 = *(const float4*)(tab + (size_t)(MODEL_CTX - 1) * 128 + 8 * m16 + 4);
    float4 qr1, qr2;
    qr1.x = q1.x * tq1.x - q2.x * tq1.y;  qr2.x = q2.x * tq1.x + q1.x * tq1.y;
    qr1.y = q1.y * tq1.z - q2.y * tq1.w;  qr2.y = q2.y * tq1.z + q1.y * tq1.w;
    qr1.z = q1.z * tq2.x - q2.z * tq2.y;  qr2.z = q2.z * tq2.x + q1.z * tq2.y;
    qr1.w = q1.w * tq2.z - q2.w * tq2.w;  qr2.w = q2.w * tq2.z + q1.w * tq2.w;

    const int t0 = chunk * CHUNK;
    const size_t head_off = (size_t)h * HEAD_DIM;
    const float scale = 0.08838834764831845f;   // 1/sqrt(128)

    // wave covers 32 tokens = 2 cache blocks
    const int bti  = b * nbps + chunk * BLKS_PER_CHUNK;
    const int blk0 = btab[bti + wave * 2];
    const int blk1 = btab[bti + wave * 2 + 1];
    const float* kb0 = kcache + (size_t)blk0 * BLOCK_SZ * HD + head_off;
    const float* kb1 = kcache + (size_t)blk1 * BLOCK_SZ * HD + head_off;
    const float* vb0 = vcache + (size_t)blk0 * BLOCK_SZ * HD + head_off;
    const float* vb1 = vcache + (size_t)blk1 * BLOCK_SZ * HD + head_off;
    const float* knb = knew + (size_t)b * HD + head_off;
    const float* vnb = vnew + (size_t)b * HD + head_off;

    const int tw = t0 + wave * 32;   // wave's first token

    // ================= phase 1: K -> scores (registers) =================
    float s[8];
    #pragma unroll
    for (int jj = 0; jj < 4; jj++) {
        const int locA = 8 * jj + g;          // 0..31 within wave
        const int locB = locA + 4;
        const int tA = tw + locA;
        const int tB = tw + locB;
        const bool nlA = (tA >= T - 1);
        const bool nlB = (tB >= T - 1);
        const float* kpA = nlA ? knb : ((locA < 16 ? kb0 : kb1) + (size_t)(locA & 15) * HD);
        const float* kpB = nlB ? knb : ((locB < 16 ? kb0 : kb1) + (size_t)(locB & 15) * HD);
        const int ttA = nlA ? (MODEL_CTX - 1) : tA;
        const int ttB = nlB ? (MODEL_CTX - 1) : tB;

        // issue the pair's 8 loads up front
        const float4 kA1 = *(const float4*)(kpA + 4 * m16);
        const float4 kA2 = *(const float4*)(kpA + 64 + 4 * m16);
        const float4 kB1 = *(const float4*)(kpB + 4 * m16);
        const float4 kB2 = *(const float4*)(kpB + 64 + 4 * m16);
        const float4 cA1 = *(const float4*)(tab + (size_t)ttA * 128 + 8 * m16);
        const float4 cA2 = *(const float4*)(tab + (size_t)ttA * 128 + 8 * m16 + 4);
        const float4 cB1 = *(const float4*)(tab + (size_t)ttB * 128 + 8 * m16);
        const float4 cB2 = *(const float4*)(tab + (size_t)ttB * 128 + 8 * m16 + 4);

        float dA =
            (kA1.x * cA1.x - kA2.x * cA1.y) * qr1.x + (kA2.x * cA1.x + kA1.x * cA1.y) * qr2.x
          + (kA1.y * cA1.z - kA2.y * cA1.w) * qr1.y + (kA2.y * cA1.z + kA1.y * cA1.w) * qr2.y
          + (kA1.z * cA2.x - kA2.z * cA2.y) * qr1.z + (kA2.z * cA2.x + kA1.z * cA2.y) * qr2.z
          + (kA1.w * cA2.z - kA2.w * cA2.w) * qr1.w + (kA2.w * cA2.z + kA1.w * cA2.w) * qr2.w;
        float dB =
            (kB1.x * cB1.x - kB2.x * cB1.y) * qr1.x + (kB2.x * cB1.x + kB1.x * cB1.y) * qr2.x
          + (kB1.y * cB1.z - kB2.y * cB1.w) * qr1.y + (kB2.y * cB1.z + kB1.y * cB1.w) * qr2.y
          + (kB1.z * cB2.x - kB2.z * cB2.y) * qr1.z + (kB2.z * cB2.x + kB1.z * cB2.y) * qr2.z
          + (kB1.w * cB2.z - kB2.w * cB2.w) * qr1.w + (kB2.w * cB2.z + kB1.w * cB2.w) * qr2.w;

        #pragma unroll
        for (int off = 1; off < 16; off <<= 1) {
            dA += __shfl_xor(dA, off, 64);
            dB += __shfl_xor(dB, off, 64);
        }
        s[2 * jj]     = (tA < T) ? dA * scale : -INFINITY;
        s[2 * jj + 1] = (tB < T) ? dB * scale : -INFINITY;
    }

    // ---- wave max (offline softmax) ----
    float m = s[0];
    #pragma unroll
    for (int i = 1; i < 8; i++) m = fmaxf(m, s[i]);
    m = fmaxf(m, __shfl_xor(m, 16, 64));
    m = fmaxf(m, __shfl_xor(m, 32, 64));     // wave-wide max, all lanes

    float p[8];
    float l = 0.f;
    #pragma unroll
    for (int i = 0; i < 8; i++) { p[i] = __expf(s[i] - m); l += p[i]; }

    __syncthreads();

    // ================= phase 2: p * V =================
    float4 o1 = {0.f, 0.f, 0.f, 0.f};
    float4 o2 = {0.f, 0.f, 0.f, 0.f};
    #pragma unroll
    for (int jj = 0; jj < 4; jj++) {
        const int locA = 8 * jj + g;
        const int locB = locA + 4;
        const int tA = tw + locA;
        const int tB = tw + locB;
        const float* vpA = (tA >= T - 1) ? vnb : ((locA < 16 ? vb0 : vb1) + (size_t)(locA & 15) * HD);
        const float* vpB = (tB >= T - 1) ? vnb : ((locB < 16 ? vb0 : vb1) + (size_t)(locB & 15) * HD);

        const float4 vA1 = *(const float4*)(vpA + 4 * m16);
        const float4 vA2 = *(const float4*)(vpA + 64 + 4 * m16);
        const float4 vB1 = *(const float4*)(vpB + 4 * m16);
        const float4 vB2 = *(const float4*)(vpB + 64 + 4 * m16);

        const float pA = p[2 * jj];
        const float pB = p[2 * jj + 1];
        o1.x += pA * vA1.x + pB * vB1.x;
        o1.y += pA * vA1.y + pB * vB1.y;
        o1.z += pA * vA1.z + pB * vB1.z;
        o1.w += pA * vA1.w + pB * vB1.w;
        o2.x += pA * vA2.x + pB * vB2.x;
        o2.y += pA * vA2.y + pB * vB2.y;
        o2.z += pA * vA2.z + pB * vB2.z;
        o2.w += pA * vA2.w + pB * vB2.w;
    }

    // ---- combine the 4 groups within the wave (same m16 = same dims) ----
    float lw = l;
    #pragma unroll
    for (int off = 16; off < 64; off <<= 1) {
        lw   += __shfl_xor(lw, off, 64);
        o1.x += __shfl_xor(o1.x, off, 64);
        o1.y += __shfl_xor(o1.y, off, 64);
        o1.z += __shfl_xor(o1.z, off, 64);
        o1.w += __shfl_xor(o1.w, off, 64);
        o2.x += __shfl_xor(o2.x, off, 64);
        o2.y += __shfl_xor(o2.y, off, 64);
        o2.z += __shfl_xor(o2.z, off, 64);
        o2.w += __shfl_xor(o2.w, off, 64);
    }

    if (g == 0) {
        *(float4*)&wo[wave][4 * m16]      = o1;
        *(float4*)&wo[wave][64 + 4 * m16] = o2;
        if (m16 == 0) { wm[wave] = m; wl[wave] = lw; }
    }
    __syncthreads();

    // ---- cross-wave combine + store partials ----
    if (tid < HEAD_DIM) {
        const float m0 = wm[0], m1 = wm[1], m2 = wm[2], m3 = wm[3];
        const float M = fmaxf(fmaxf(m0, m1), fmaxf(m2, m3));
        const float w0 = __expf(m0 - M), w1 = __expf(m1 - M);
        const float w2 = __expf(m2 - M), w3 = __expf(m3 - M);
        const float num = w0 * wo[0][tid] + w1 * wo[1][tid]
                        + w2 * wo[2][tid] + w3 * wo[3][tid];
        o_part[((size_t)bh * n_chunks + chunk) * HEAD_DIM + tid] = num;
        if (tid == 0) {
            m_part[bh * n_chunks + chunk] = M;
            l_part[bh * n_chunks + chunk] = w0 * wl[0] + w1 * wl[1] + w2 * wl[2] + w3 * wl[3];
        }
    }
}

// Kernel 2: combine split-K partials.
__global__ void attn_combine(const float* __restrict__ o_part,
                             const float* __restrict__ m_part,
                             const float* __restrict__ l_part,
                             float* __restrict__ out,
                             int n_chunks)
{
    const int bh = blockIdx.x;
    const int d  = threadIdx.x;

    float M = -INFINITY;
    for (int c = 0; c < n_chunks; c++) M = fmaxf(M, m_part[bh * n_chunks + c]);
    float L = 0.f, num = 0.f;
    for (int c = 0; c < n_chunks; c++) {
        const float w = __expf(m_part[bh * n_chunks + c] - M);
        L   += l_part[bh * n_chunks + c] * w;
        num += w * o_part[((size_t)bh * n_chunks + c) * HEAD_DIM + d];
    }
    out[(size_t)bh * HEAD_DIM + d] = num / L;
}

extern "C" void kernel_launch(void* const* d_in, const int* in_sizes, int n_in,
                              void* d_out, int out_size, void* d_ws, size_t ws_size,
                              hipStream_t stream) {
    const float* q  = (const float*)d_in[0];
    const float* k  = (const float*)d_in[1];
    const float* v  = (const float*)d_in[2];
    const float* kc = (const float*)d_in[3];
    const float* vc = (const float*)d_in[4];
    const int* bt   = (const int*)d_in[5];
    const int* slp  = (const int*)d_in[7];

    const int B    = in_sizes[0] / HD;
    const int nbps = in_sizes[5] / B;                              // 256
    const int n_chunks = (nbps * BLOCK_SZ + CHUNK - 1) / CHUNK;    // 32
    const int BH = B * NUM_KV_HEADS;

    int ntab = nbps * BLOCK_SZ;
    if (ntab < MODEL_CTX) ntab = MODEL_CTX;

    float* tab    = (float*)d_ws;                                   // ntab*64*2 floats
    float* o_part = tab + (size_t)ntab * 128;
    float* m_part = o_part + (size_t)BH * n_chunks * HEAD_DIM;
    float* l_part = m_part + (size_t)BH * n_chunks;

    const int ttotal = ntab * 64;
    rope_table<<<(ttotal + 255) / 256, 256, 0, stream>>>(tab, ntab);

    dim3 g1(n_chunks, BH);
    attn_partial<<<g1, 256, 0, stream>>>(q, k, v, kc, vc, bt, slp, tab, nbps,
                                         o_part, m_part, l_part, n_chunks);
    attn_combine<<<dim3(BH), HEAD_DIM, 0, stream>>>(o_part, m_part, l_part,
                                                    (float*)d_out, n_chunks);
}